// Round 14
// baseline (327.604 us; speedup 1.0000x reference)
//
#include <hip/hip_runtime.h>
#include <hip/hip_bf16.h>
#include <math.h>

#define HN 39
#define WN 39
#define NBATCH 128
#define NPIX (HN * WN)          // 1521
#define NNODE (NBATCH * WN)     // 4992
#define E_RAW 200064
#define E_TOT (E_RAW + NNODE)   // 205056
#define F1 512
#define F2 64
#define CROWS 6                 // conv output rows per block
#define GIPL (NBATCH * NPIX)    // gi plane stride = 194688

static __device__ __forceinline__ float nan0(float x) { return (x == x) ? x : 0.f; }
static __device__ __forceinline__ float sigmoid_f(float x) { return 1.f / (1.f + __expf(-x)); }
static __device__ __forceinline__ float tanh_f(float x) {
    float e = __expf(2.f * x);
    return 1.f - 2.f / (e + 1.f);
}

#define BN_RSQ 0.99999500003749969f   // 1/sqrt(1+1e-5)

// ---------------------------------------------------------------------------
// K1: fused nan-clean + conv1(1x1)+BN+ReLU + conv2(3x3)+BN + GRU input proj.
// R14: gi written as 3 planes (coalesced for gru); man-half of xn written
// here in phase 1 (conv already loads man; saves gru a 2nd memory pass).
// ---------------------------------------------------------------------------
__global__ __launch_bounds__(256) void conv_kernel(
    const float* __restrict__ ve, const float* __restrict__ ac, const float* __restrict__ man,
    const float* __restrict__ c1w, const float* __restrict__ c1b,
    const float* __restrict__ bn1g, const float* __restrict__ bn1b,
    const float* __restrict__ c2w, const float* __restrict__ c2b,
    const float* __restrict__ bn2g, const float* __restrict__ bn2b,
    const float* __restrict__ wih, const float* __restrict__ bih,
    const float* __restrict__ maskv,
    float* __restrict__ gi_out,      // 3 planes of (B,1521)
    float* __restrict__ xn)          // (NNODE, 78)
{
    __shared__ float y1[8][(CROWS + 2) * WN + 8];
    const int b = blockIdx.x;
    const int r0 = blockIdx.y * CROWS;
    const int tid = threadIdx.x;

    for (int p = tid; p < (CROWS + 2) * WN; p += 256) {
        const int row = p / WN;
        const int hh = r0 - 1 + row;
        if (hh < 0 || hh >= HN) continue;
        const int w = p - row * WN;
        const int gidx = b * NPIX + hh * WN + w;
        const float m = nan0(man[gidx]);
        const float a = nan0(ac[gidx]);
        const float v = nan0(ve[gidx]);
        if (hh >= r0 && hh < r0 + CROWS)   // man-half of xn for this block's rows
            xn[(size_t)(b * WN + w) * 78 + hh] = m * maskv[b * WN + w];
#pragma unroll
        for (int c = 0; c < 8; ++c) {
            float val = c1w[c * 3 + 0] * m + c1w[c * 3 + 1] * a + c1w[c * 3 + 2] * v + c1b[c];
            val = val * (bn1g[c] * BN_RSQ) + bn1b[c];
            y1[c][p] = fmaxf(val, 0.f);
        }
    }
    __syncthreads();

    for (int p = tid; p < CROWS * WN; p += 256) {
        const int h = r0 + p / WN;
        if (h >= HN) continue;
        const int w = p - (p / WN) * WN;
        float acc[16];
#pragma unroll
        for (int o = 0; o < 16; ++o) acc[o] = 0.f;
        for (int c = 0; c < 8; ++c) {
#pragma unroll
            for (int dy = 0; dy < 3; ++dy) {
                const int hh = h + dy - 1;
                if (hh < 0 || hh >= HN) continue;
                const int lrow = hh - r0 + 1;
#pragma unroll
                for (int dx = 0; dx < 3; ++dx) {
                    const int ww = w + dx - 1;
                    if (ww < 0 || ww >= WN) continue;
                    const float yv = y1[c][lrow * WN + ww];
#pragma unroll
                    for (int o = 0; o < 16; ++o)
                        acc[o] = fmaf(c2w[((o * 8 + c) * 3 + dy) * 3 + dx], yv, acc[o]);
                }
            }
        }
        float gi0 = bih[0], gi1 = bih[1], gi2 = bih[2];
#pragma unroll
        for (int o = 0; o < 16; ++o) {
            const float x2 = (acc[o] + c2b[o]) * (bn2g[o] * BN_RSQ) + bn2b[o];
            gi0 = fmaf(wih[0 * 16 + o], x2, gi0);
            gi1 = fmaf(wih[1 * 16 + o], x2, gi1);
            gi2 = fmaf(wih[2 * 16 + o], x2, gi2);
        }
        const int idx = b * NPIX + h * WN + w;
        gi_out[idx] = gi0;
        gi_out[GIPL + idx] = gi1;
        gi_out[2 * GIPL + idx] = gi2;
    }
}

// ---------------------------------------------------------------------------
// K2 (R14): GRU recurrence only (man-half moved to conv). 78 blocks x 64 thr
// (was 20x256 — 4x more CUs in flight); 3-step unroll, loads issued up-front
// (3x latency amortization); gi plane reads are stride-4B coalesced.
// ---------------------------------------------------------------------------
__global__ __launch_bounds__(64) void gru_kernel(
    const float* __restrict__ gi, const float* __restrict__ whh, const float* __restrict__ bhh,
    const float* __restrict__ maskv, float* __restrict__ xn)
{
    const int idx = blockIdx.x * 64 + threadIdx.x;
    if (idx >= NNODE) return;
    const int b = idx / WN, w = idx - (idx / WN) * WN;
    const float mk = maskv[idx];
    float* __restrict__ xrow = xn + (size_t)idx * 78 + HN;

    const float* __restrict__ g0 = gi + b * NPIX + w;
    const float* __restrict__ g1 = g0 + GIPL;
    const float* __restrict__ g2 = g0 + 2 * GIPL;

    const float wh0 = whh[0], wh1 = whh[1], wh2 = whh[2];
    const float bh0 = bhh[0], bh1 = bhh[1], bh2 = bhh[2];
    float h = 0.f;
#pragma unroll 1
    for (int t = 0; t < HN; t += 3) {       // 39 = 13 * 3
        const float ga0 = g0[t * WN],       ga1 = g1[t * WN],       ga2 = g2[t * WN];
        const float gb0 = g0[(t + 1) * WN], gb1 = g1[(t + 1) * WN], gb2 = g2[(t + 1) * WN];
        const float gc0 = g0[(t + 2) * WN], gc1 = g1[(t + 2) * WN], gc2 = g2[(t + 2) * WN];

        float r = sigmoid_f(ga0 + h * wh0 + bh0);
        float z = sigmoid_f(ga1 + h * wh1 + bh1);
        float n = tanh_f(ga2 + r * (h * wh2 + bh2));
        h = (1.f - z) * n + z * h;
        xrow[t] = h * mk;

        r = sigmoid_f(gb0 + h * wh0 + bh0);
        z = sigmoid_f(gb1 + h * wh1 + bh1);
        n = tanh_f(gb2 + r * (h * wh2 + bh2));
        h = (1.f - z) * n + z * h;
        xrow[t + 1] = h * mk;

        r = sigmoid_f(gc0 + h * wh0 + bh0);
        z = sigmoid_f(gc1 + h * wh1 + bh1);
        n = tanh_f(gc2 + r * (h * wh2 + bh2));
        h = (1.f - z) * n + z * h;
        xrow[t + 2] = h * mk;
    }
}

// ---------------------------------------------------------------------------
// K4: CSR build (histogram -> scan -> scatter)
// ---------------------------------------------------------------------------
__global__ __launch_bounds__(256) void edge_hist(const int* __restrict__ ei, int* __restrict__ counts)
{
    const int e = blockIdx.x * 256 + threadIdx.x;
    if (e >= E_TOT) return;
    const int d = (e < E_RAW) ? ei[E_RAW + e] : (e - E_RAW);
    atomicAdd(&counts[d], 1);
}

__global__ __launch_bounds__(256) void scan_kernel(const int* __restrict__ counts,
                                                   int* __restrict__ offsets, int* __restrict__ cursor)
{
    __shared__ int sums[256];
    const int tid = threadIdx.x;
    const int start = tid * 20;
    const int end = min(start + 20, NNODE);
    int s = 0;
    for (int i = start; i < end; ++i) s += counts[i];
    sums[tid] = s;
    __syncthreads();
    for (int off = 1; off < 256; off <<= 1) {
        int v = (tid >= off) ? sums[tid - off] : 0;
        __syncthreads();
        sums[tid] += v;
        __syncthreads();
    }
    int run = (tid == 0) ? 0 : sums[tid - 1];
    for (int i = start; i < end; ++i) {
        offsets[i] = run;
        cursor[i] = run;
        run += counts[i];
    }
    if (tid == 255) offsets[NNODE] = run;
}

__global__ __launch_bounds__(256) void edge_scatter(const int* __restrict__ ei,
                                                    int* __restrict__ cursor,
                                                    int* __restrict__ srcs)
{
    const int e = blockIdx.x * 256 + threadIdx.x;
    if (e >= E_TOT) return;
    int s, d;
    if (e < E_RAW) { s = ei[e]; d = ei[E_RAW + e]; }
    else           { s = d = e - E_RAW; }
    const int pos = atomicAdd(&cursor[d], 1);
    srcs[pos] = s;
}

// ---------------------------------------------------------------------------
// K5: tiled f32 GEMM (R1 unroll cap). R14: NZ=1 everywhere — split-K's
// partial+reduce path replaced; A/B vs R13's 12+3 us + extra node.
// ---------------------------------------------------------------------------
template <int K, int NZ>
__global__ __launch_bounds__(256, 4) void gemm_kernel(
    const float* __restrict__ X,
    const float* __restrict__ Wl, const float* __restrict__ bl,
    const float* __restrict__ Wr, const float* __restrict__ br,
    float* __restrict__ Yl, float* __restrict__ Yr, int J)
{
    const int nyb = J >> 6;
    const int sel = (blockIdx.y >= nyb) ? 1 : 0;
    const int j0 = (blockIdx.y - sel * nyb) * 64;
    const float* __restrict__ W = sel ? Wr : Wl;
    const float* __restrict__ bias = sel ? br : bl;
    float* __restrict__ Y;
    if (NZ == 1) Y = sel ? Yr : Yl;
    else         Y = Yl + ((size_t)blockIdx.z * 2 + sel) * ((size_t)NNODE * J);

    __shared__ __align__(16) float Xs[32][68];
    __shared__ __align__(16) float Ws[32][68];

    const int kchunk = K / NZ;
    const int kbeg = blockIdx.z * kchunk;
    const int kend = (blockIdx.z == NZ - 1) ? K : kbeg + kchunk;

    const int m0 = blockIdx.x * 64;
    const int tid = threadIdx.x;
    const int ti = tid / 16, tj = tid & 15;
    const int lrow = tid >> 2;
    const int ks = (tid & 3) * 8;

    float acc[4][4];
#pragma unroll
    for (int i = 0; i < 4; ++i)
#pragma unroll
        for (int j = 0; j < 4; ++j) acc[i][j] = 0.f;

    for (int k0 = kbeg; k0 < kend; k0 += 32) {
        const float* xp = X + (size_t)(m0 + lrow) * K + k0 + ks;
        const float* wp = W + (size_t)(j0 + lrow) * K + k0 + ks;
#pragma unroll
        for (int q = 0; q < 8; ++q) {
            const int k = k0 + ks + q;
            Xs[ks + q][lrow] = (k < K) ? xp[q] : 0.f;
            Ws[ks + q][lrow] = (k < K) ? wp[q] : 0.f;
        }
        __syncthreads();
#pragma unroll 8
        for (int kk = 0; kk < 32; ++kk) {
            const float4 xv = *(const float4*)&Xs[kk][ti * 4];
            const float4 wv = *(const float4*)&Ws[kk][tj * 4];
            acc[0][0] = fmaf(xv.x, wv.x, acc[0][0]);
            acc[0][1] = fmaf(xv.x, wv.y, acc[0][1]);
            acc[0][2] = fmaf(xv.x, wv.z, acc[0][2]);
            acc[0][3] = fmaf(xv.x, wv.w, acc[0][3]);
            acc[1][0] = fmaf(xv.y, wv.x, acc[1][0]);
            acc[1][1] = fmaf(xv.y, wv.y, acc[1][1]);
            acc[1][2] = fmaf(xv.y, wv.z, acc[1][2]);
            acc[1][3] = fmaf(xv.y, wv.w, acc[1][3]);
            acc[2][0] = fmaf(xv.z, wv.x, acc[2][0]);
            acc[2][1] = fmaf(xv.z, wv.y, acc[2][1]);
            acc[2][2] = fmaf(xv.z, wv.z, acc[2][2]);
            acc[2][3] = fmaf(xv.z, wv.w, acc[2][3]);
            acc[3][0] = fmaf(xv.w, wv.x, acc[3][0]);
            acc[3][1] = fmaf(xv.w, wv.y, acc[3][1]);
            acc[3][2] = fmaf(xv.w, wv.z, acc[3][2]);
            acc[3][3] = fmaf(xv.w, wv.w, acc[3][3]);
        }
        __syncthreads();
    }
#pragma unroll
    for (int i = 0; i < 4; ++i) {
        const int m = m0 + ti * 4 + i;
#pragma unroll
        for (int j = 0; j < 4; ++j) {
            const int jj = j0 + tj * 4 + j;
            if (NZ == 1) Y[(size_t)m * J + jj] = acc[i][j] + bias[jj];
            else         Y[(size_t)m * J + jj] = acc[i][j];
        }
    }
}

// ---------------------------------------------------------------------------
// K6: single-pass no-max softmax GATv2 (R12/R13 — at random-gather traffic
// floor: 135 MB compulsory @ 2.79 TB/s). Wave = (node, head); 4 edge-groups
// of 16 lanes; no-max weights exact in f32 (|logit| <~ 10); no LDS.
// ---------------------------------------------------------------------------
template <int FDIM>
static __device__ __forceinline__ void gat_nomax(
    const float* __restrict__ xl, const int* __restrict__ srcs,
    int base, int deg, int hoff, int lane, float4 xrv, float4 av,
    float4& accOut, float& lOut)
{
    const int e4 = lane >> 4;
    const int c4 = lane & 15;
    float l = 0.f;
    float4 acc = make_float4(0.f, 0.f, 0.f, 0.f);

    for (int c0 = 0; c0 < deg; c0 += 8) {
        const int eA = c0 + e4;
        const int eB = c0 + 4 + e4;
        const int sA = srcs[base + min(eA, deg - 1)];
        const int sB = srcs[base + min(eB, deg - 1)];
        const float4 xaA = *(const float4*)(xl + (size_t)sA * FDIM + hoff + c4 * 4);
        const float4 xaB = *(const float4*)(xl + (size_t)sB * FDIM + hoff + c4 * 4);

        float a0 = xaA.x + xrv.x; a0 = fmaxf(a0, 0.2f * a0);
        float a1 = xaA.y + xrv.y; a1 = fmaxf(a1, 0.2f * a1);
        float a2 = xaA.z + xrv.z; a2 = fmaxf(a2, 0.2f * a2);
        float a3 = xaA.w + xrv.w; a3 = fmaxf(a3, 0.2f * a3);
        float pA = av.x * a0 + av.y * a1 + av.z * a2 + av.w * a3;
        float b0 = xaB.x + xrv.x; b0 = fmaxf(b0, 0.2f * b0);
        float b1 = xaB.y + xrv.y; b1 = fmaxf(b1, 0.2f * b1);
        float b2 = xaB.z + xrv.z; b2 = fmaxf(b2, 0.2f * b2);
        float b3 = xaB.w + xrv.w; b3 = fmaxf(b3, 0.2f * b3);
        float pB = av.x * b0 + av.y * b1 + av.z * b2 + av.w * b3;

        pA += __shfl_xor(pA, 1, 64);
        pA += __shfl_xor(pA, 2, 64);
        pA += __shfl_xor(pA, 4, 64);
        pA += __shfl_xor(pA, 8, 64);
        pB += __shfl_xor(pB, 1, 64);
        pB += __shfl_xor(pB, 2, 64);
        pB += __shfl_xor(pB, 4, 64);
        pB += __shfl_xor(pB, 8, 64);

        const float wA = (eA < deg) ? __expf(pA) : 0.f;
        const float wB = (eB < deg) ? __expf(pB) : 0.f;
        l += wA + wB;
        acc.x = fmaf(wA, xaA.x, fmaf(wB, xaB.x, acc.x));
        acc.y = fmaf(wA, xaA.y, fmaf(wB, xaB.y, acc.y));
        acc.z = fmaf(wA, xaA.z, fmaf(wB, xaB.z, acc.z));
        acc.w = fmaf(wA, xaA.w, fmaf(wB, xaB.w, acc.w));
    }

    l += __shfl_xor(l, 16, 64);
    l += __shfl_xor(l, 32, 64);
    acc.x += __shfl_xor(acc.x, 16, 64);
    acc.y += __shfl_xor(acc.y, 16, 64);
    acc.z += __shfl_xor(acc.z, 16, 64);
    acc.w += __shfl_xor(acc.w, 16, 64);
    acc.x += __shfl_xor(acc.x, 32, 64);
    acc.y += __shfl_xor(acc.y, 32, 64);
    acc.z += __shfl_xor(acc.z, 32, 64);
    acc.w += __shfl_xor(acc.w, 32, 64);
    accOut = acc;
    lOut = l;
}

__global__ __launch_bounds__(512) void gat1_fused_kernel(
    const float* __restrict__ xl, const float* __restrict__ xr,
    const float* __restrict__ att, const float* __restrict__ bias,
    const int* __restrict__ offsets, const int* __restrict__ srcs,
    float* __restrict__ h1)
{
    const int n = blockIdx.x;
    const int h = threadIdx.x >> 6;
    const int lane = threadIdx.x & 63;
    const int base = offsets[n];
    const int deg = offsets[n + 1] - base;
    const int c4 = lane & 15;

    const float4 xrv = *(const float4*)(xr + (size_t)n * F1 + h * 64 + c4 * 4);
    const float4 av  = *(const float4*)(att + h * 64 + c4 * 4);

    float4 acc; float l;
    gat_nomax<F1>(xl, srcs, base, deg, h * 64, lane, xrv, av, acc, l);

    if ((lane >> 4) == 0) {
        const float inv = 1.f / l;
        const float4 bv = *(const float4*)(bias + h * 64 + c4 * 4);
        float4 o;
        o.x = acc.x * inv + bv.x; o.x = (o.x > 0.f) ? o.x : expm1f(o.x);
        o.y = acc.y * inv + bv.y; o.y = (o.y > 0.f) ? o.y : expm1f(o.y);
        o.z = acc.z * inv + bv.z; o.z = (o.z > 0.f) ? o.z : expm1f(o.z);
        o.w = acc.w * inv + bv.w; o.w = (o.w > 0.f) ? o.w : expm1f(o.w);
        *(float4*)(h1 + (size_t)n * F1 + h * 64 + c4 * 4) = o;
    }
}

__global__ __launch_bounds__(256) void gat2_fused_kernel(
    const float* __restrict__ xl, const float* __restrict__ xr,
    const float* __restrict__ att, const float* __restrict__ bias,
    const int* __restrict__ offsets, const int* __restrict__ srcs,
    float* __restrict__ out)
{
    const int wv = threadIdx.x >> 6;
    const int lane = threadIdx.x & 63;
    const int n = blockIdx.x * 4 + wv;
    const int base = offsets[n];
    const int deg = offsets[n + 1] - base;
    const int c4 = lane & 15;

    const float4 xrv = *(const float4*)(xr + (size_t)n * F2 + c4 * 4);
    const float4 av  = *(const float4*)(att + c4 * 4);

    float4 acc; float l;
    gat_nomax<F2>(xl, srcs, base, deg, 0, lane, xrv, av, acc, l);

    if ((lane >> 4) == 0) {
        const float inv = 1.f / l;
        const float4 bv = *(const float4*)(bias + c4 * 4);
        float4 o;
        o.x = acc.x * inv + bv.x;
        o.y = acc.y * inv + bv.y;
        o.z = acc.z * inv + bv.z;
        o.w = acc.w * inv + bv.w;
        *(float4*)(out + (size_t)n * F2 + c4 * 4) = o;
    }
}

// ---------------------------------------------------------------------------
extern "C" void kernel_launch(void* const* d_in, const int* in_sizes, int n_in,
                              void* d_out, int out_size, void* d_ws, size_t ws_size,
                              hipStream_t stream)
{
    const int*   ei    = (const int*)d_in[0];
    const float* ve    = (const float*)d_in[1];
    const float* ac    = (const float*)d_in[2];
    const float* man   = (const float*)d_in[3];
    const float* maskv = (const float*)d_in[4];
    const float* c1w   = (const float*)d_in[6];
    const float* c1b   = (const float*)d_in[7];
    const float* bn1g  = (const float*)d_in[8];
    const float* bn1b  = (const float*)d_in[9];
    const float* c2w   = (const float*)d_in[10];
    const float* c2b   = (const float*)d_in[11];
    const float* bn2g  = (const float*)d_in[12];
    const float* bn2b  = (const float*)d_in[13];
    const float* wih   = (const float*)d_in[14];
    const float* whh   = (const float*)d_in[15];
    const float* bih   = (const float*)d_in[16];
    const float* bhh   = (const float*)d_in[17];
    const float* g1wl  = (const float*)d_in[18];
    const float* g1bl  = (const float*)d_in[19];
    const float* g1wr  = (const float*)d_in[20];
    const float* g1br  = (const float*)d_in[21];
    const float* g1att = (const float*)d_in[22];
    const float* g1bias= (const float*)d_in[23];
    const float* g2wl  = (const float*)d_in[24];
    const float* g2bl  = (const float*)d_in[25];
    const float* g2wr  = (const float*)d_in[26];
    const float* g2br  = (const float*)d_in[27];
    const float* g2att = (const float*)d_in[28];
    const float* g2bias= (const float*)d_in[29];
    float* outp = (float*)d_out;

    // workspace layout (floats)
    float* ws     = (float*)d_ws;
    float* gi     = ws;                         // 3 * 194688 = 584064
    float* xn     = gi     + 584064;            // 389376
    float* xl1    = xn     + 389376;            // 2555904
    float* xr1    = xl1    + 2555904;           // 2555904
    float* h1     = xr1    + 2555904;           // 2555904
    float* xl2    = h1     + 2555904;           // 319488
    float* xr2    = xl2    + 319488;            // 319488
    int* counts  = (int*)(xr2 + 319488);        // 4992
    int* offsets = counts + NNODE;              // 4993
    int* cursor  = offsets + NNODE + 1;         // 4992
    int* srcs    = cursor + NNODE;              // 205056

    hipMemsetAsync(counts, 0, NNODE * sizeof(int), stream);

    conv_kernel<<<dim3(NBATCH, (HN + CROWS - 1) / CROWS), 256, 0, stream>>>(
        ve, ac, man, c1w, c1b, bn1g, bn1b, c2w, c2b, bn2g, bn2b, wih, bih,
        maskv, gi, xn);
    gru_kernel<<<(NNODE + 63) / 64, 64, 0, stream>>>(gi, whh, bhh, maskv, xn);

    edge_hist<<<(E_TOT + 255) / 256, 256, 0, stream>>>(ei, counts);
    scan_kernel<<<1, 256, 0, stream>>>(counts, offsets, cursor);
    edge_scatter<<<(E_TOT + 255) / 256, 256, 0, stream>>>(ei, cursor, srcs);

    gemm_kernel<78, 1><<<dim3(NNODE / 64, 2 * (F1 / 64)), 256, 0, stream>>>(
        xn, g1wl, g1bl, g1wr, g1br, xl1, xr1, F1);

    gat1_fused_kernel<<<NNODE, 512, 0, stream>>>(xl1, xr1, g1att, g1bias, offsets, srcs, h1);

    gemm_kernel<512, 1><<<dim3(NNODE / 64, 2 * (F2 / 64)), 256, 0, stream>>>(
        h1, g2wl, g2bl, g2wr, g2br, xl2, xr2, F2);

    gat2_fused_kernel<<<NNODE / 4, 256, 0, stream>>>(xl2, xr2, g2att, g2bias, offsets, srcs, outp);
}

// Round 15
// 306.224 us; speedup vs baseline: 1.0698x; 1.0698x over previous
//
#include <hip/hip_runtime.h>
#include <hip/hip_bf16.h>
#include <math.h>

#define HN 39
#define WN 39
#define NBATCH 128
#define NPIX (HN * WN)          // 1521
#define NNODE (NBATCH * WN)     // 4992
#define E_RAW 200064
#define E_TOT (E_RAW + NNODE)   // 205056
#define F1 512
#define F2 64
#define CROWS 6                 // conv output rows per block
#define GIPL (NBATCH * NPIX)    // gi plane stride = 194688

static __device__ __forceinline__ float nan0(float x) { return (x == x) ? x : 0.f; }
static __device__ __forceinline__ float sigmoid_f(float x) { return 1.f / (1.f + __expf(-x)); }
static __device__ __forceinline__ float tanh_f(float x) {
    float e = __expf(2.f * x);
    return 1.f - 2.f / (e + 1.f);
}

#define BN_RSQ 0.99999500003749969f   // 1/sqrt(1+1e-5)

// ---------------------------------------------------------------------------
// K1: fused nan-clean + conv1(1x1)+BN+ReLU + conv2(3x3)+BN + GRU input proj.
// gi written as 3 planes (coalesced for gru); man-half of xn written here.
// ---------------------------------------------------------------------------
__global__ __launch_bounds__(256) void conv_kernel(
    const float* __restrict__ ve, const float* __restrict__ ac, const float* __restrict__ man,
    const float* __restrict__ c1w, const float* __restrict__ c1b,
    const float* __restrict__ bn1g, const float* __restrict__ bn1b,
    const float* __restrict__ c2w, const float* __restrict__ c2b,
    const float* __restrict__ bn2g, const float* __restrict__ bn2b,
    const float* __restrict__ wih, const float* __restrict__ bih,
    const float* __restrict__ maskv,
    float* __restrict__ gi_out,      // 3 planes of (B,1521)
    float* __restrict__ xn)          // (NNODE, 78)
{
    __shared__ float y1[8][(CROWS + 2) * WN + 8];
    const int b = blockIdx.x;
    const int r0 = blockIdx.y * CROWS;
    const int tid = threadIdx.x;

    for (int p = tid; p < (CROWS + 2) * WN; p += 256) {
        const int row = p / WN;
        const int hh = r0 - 1 + row;
        if (hh < 0 || hh >= HN) continue;
        const int w = p - row * WN;
        const int gidx = b * NPIX + hh * WN + w;
        const float m = nan0(man[gidx]);
        const float a = nan0(ac[gidx]);
        const float v = nan0(ve[gidx]);
        if (hh >= r0 && hh < r0 + CROWS)
            xn[(size_t)(b * WN + w) * 78 + hh] = m * maskv[b * WN + w];
#pragma unroll
        for (int c = 0; c < 8; ++c) {
            float val = c1w[c * 3 + 0] * m + c1w[c * 3 + 1] * a + c1w[c * 3 + 2] * v + c1b[c];
            val = val * (bn1g[c] * BN_RSQ) + bn1b[c];
            y1[c][p] = fmaxf(val, 0.f);
        }
    }
    __syncthreads();

    for (int p = tid; p < CROWS * WN; p += 256) {
        const int h = r0 + p / WN;
        if (h >= HN) continue;
        const int w = p - (p / WN) * WN;
        float acc[16];
#pragma unroll
        for (int o = 0; o < 16; ++o) acc[o] = 0.f;
        for (int c = 0; c < 8; ++c) {
#pragma unroll
            for (int dy = 0; dy < 3; ++dy) {
                const int hh = h + dy - 1;
                if (hh < 0 || hh >= HN) continue;
                const int lrow = hh - r0 + 1;
#pragma unroll
                for (int dx = 0; dx < 3; ++dx) {
                    const int ww = w + dx - 1;
                    if (ww < 0 || ww >= WN) continue;
                    const float yv = y1[c][lrow * WN + ww];
#pragma unroll
                    for (int o = 0; o < 16; ++o)
                        acc[o] = fmaf(c2w[((o * 8 + c) * 3 + dy) * 3 + dx], yv, acc[o]);
                }
            }
        }
        float gi0 = bih[0], gi1 = bih[1], gi2 = bih[2];
#pragma unroll
        for (int o = 0; o < 16; ++o) {
            const float x2 = (acc[o] + c2b[o]) * (bn2g[o] * BN_RSQ) + bn2b[o];
            gi0 = fmaf(wih[0 * 16 + o], x2, gi0);
            gi1 = fmaf(wih[1 * 16 + o], x2, gi1);
            gi2 = fmaf(wih[2 * 16 + o], x2, gi2);
        }
        const int idx = b * NPIX + h * WN + w;
        gi_out[idx] = gi0;
        gi_out[GIPL + idx] = gi1;
        gi_out[2 * GIPL + idx] = gi2;
    }
}

// ---------------------------------------------------------------------------
// K2: GRU recurrence only; 78 blocks x 64 thr; 3-step unroll; plane reads.
// ---------------------------------------------------------------------------
__global__ __launch_bounds__(64) void gru_kernel(
    const float* __restrict__ gi, const float* __restrict__ whh, const float* __restrict__ bhh,
    const float* __restrict__ maskv, float* __restrict__ xn)
{
    const int idx = blockIdx.x * 64 + threadIdx.x;
    if (idx >= NNODE) return;
    const int b = idx / WN, w = idx - (idx / WN) * WN;
    const float mk = maskv[idx];
    float* __restrict__ xrow = xn + (size_t)idx * 78 + HN;

    const float* __restrict__ g0 = gi + b * NPIX + w;
    const float* __restrict__ g1 = g0 + GIPL;
    const float* __restrict__ g2 = g0 + 2 * GIPL;

    const float wh0 = whh[0], wh1 = whh[1], wh2 = whh[2];
    const float bh0 = bhh[0], bh1 = bhh[1], bh2 = bhh[2];
    float h = 0.f;
#pragma unroll 1
    for (int t = 0; t < HN; t += 3) {       // 39 = 13 * 3
        const float ga0 = g0[t * WN],       ga1 = g1[t * WN],       ga2 = g2[t * WN];
        const float gb0 = g0[(t + 1) * WN], gb1 = g1[(t + 1) * WN], gb2 = g2[(t + 1) * WN];
        const float gc0 = g0[(t + 2) * WN], gc1 = g1[(t + 2) * WN], gc2 = g2[(t + 2) * WN];

        float r = sigmoid_f(ga0 + h * wh0 + bh0);
        float z = sigmoid_f(ga1 + h * wh1 + bh1);
        float n = tanh_f(ga2 + r * (h * wh2 + bh2));
        h = (1.f - z) * n + z * h;
        xrow[t] = h * mk;

        r = sigmoid_f(gb0 + h * wh0 + bh0);
        z = sigmoid_f(gb1 + h * wh1 + bh1);
        n = tanh_f(gb2 + r * (h * wh2 + bh2));
        h = (1.f - z) * n + z * h;
        xrow[t + 1] = h * mk;

        r = sigmoid_f(gc0 + h * wh0 + bh0);
        z = sigmoid_f(gc1 + h * wh1 + bh1);
        n = tanh_f(gc2 + r * (h * wh2 + bh2));
        h = (1.f - z) * n + z * h;
        xrow[t + 2] = h * mk;
    }
}

// ---------------------------------------------------------------------------
// K4: CSR build (histogram -> scan -> scatter)
// ---------------------------------------------------------------------------
__global__ __launch_bounds__(256) void edge_hist(const int* __restrict__ ei, int* __restrict__ counts)
{
    const int e = blockIdx.x * 256 + threadIdx.x;
    if (e >= E_TOT) return;
    const int d = (e < E_RAW) ? ei[E_RAW + e] : (e - E_RAW);
    atomicAdd(&counts[d], 1);
}

__global__ __launch_bounds__(256) void scan_kernel(const int* __restrict__ counts,
                                                   int* __restrict__ offsets, int* __restrict__ cursor)
{
    __shared__ int sums[256];
    const int tid = threadIdx.x;
    const int start = tid * 20;
    const int end = min(start + 20, NNODE);
    int s = 0;
    for (int i = start; i < end; ++i) s += counts[i];
    sums[tid] = s;
    __syncthreads();
    for (int off = 1; off < 256; off <<= 1) {
        int v = (tid >= off) ? sums[tid - off] : 0;
        __syncthreads();
        sums[tid] += v;
        __syncthreads();
    }
    int run = (tid == 0) ? 0 : sums[tid - 1];
    for (int i = start; i < end; ++i) {
        offsets[i] = run;
        cursor[i] = run;
        run += counts[i];
    }
    if (tid == 255) offsets[NNODE] = run;
}

__global__ __launch_bounds__(256) void edge_scatter(const int* __restrict__ ei,
                                                    int* __restrict__ cursor,
                                                    int* __restrict__ srcs)
{
    const int e = blockIdx.x * 256 + threadIdx.x;
    if (e >= E_TOT) return;
    int s, d;
    if (e < E_RAW) { s = ei[e]; d = ei[E_RAW + e]; }
    else           { s = d = e - E_RAW; }
    const int pos = atomicAdd(&cursor[d], 1);
    srcs[pos] = s;
}

// ---------------------------------------------------------------------------
// K5: tiled f32 GEMM. R15: split-K NZ=8 with DISJOINT partials reinstated —
// R14 measured NZ=1 at 64 us / Occupancy 6.6% (156 blocks on 256 CUs,
// grid-starved). 1248 blocks; partials overlay dead xl1+xr1; bias in reduce.
// ---------------------------------------------------------------------------
template <int K, int NZ>
__global__ __launch_bounds__(256, 4) void gemm_kernel(
    const float* __restrict__ X,
    const float* __restrict__ Wl, const float* __restrict__ bl,
    const float* __restrict__ Wr, const float* __restrict__ br,
    float* __restrict__ Yl, float* __restrict__ Yr, int J)
{
    const int nyb = J >> 6;
    const int sel = (blockIdx.y >= nyb) ? 1 : 0;
    const int j0 = (blockIdx.y - sel * nyb) * 64;
    const float* __restrict__ W = sel ? Wr : Wl;
    const float* __restrict__ bias = sel ? br : bl;
    float* __restrict__ Y;
    if (NZ == 1) Y = sel ? Yr : Yl;
    else         Y = Yl + ((size_t)blockIdx.z * 2 + sel) * ((size_t)NNODE * J);

    __shared__ __align__(16) float Xs[32][68];
    __shared__ __align__(16) float Ws[32][68];

    const int kchunk = K / NZ;
    const int kbeg = blockIdx.z * kchunk;
    const int kend = (blockIdx.z == NZ - 1) ? K : kbeg + kchunk;

    const int m0 = blockIdx.x * 64;
    const int tid = threadIdx.x;
    const int ti = tid / 16, tj = tid & 15;
    const int lrow = tid >> 2;
    const int ks = (tid & 3) * 8;

    float acc[4][4];
#pragma unroll
    for (int i = 0; i < 4; ++i)
#pragma unroll
        for (int j = 0; j < 4; ++j) acc[i][j] = 0.f;

    for (int k0 = kbeg; k0 < kend; k0 += 32) {
        const float* xp = X + (size_t)(m0 + lrow) * K + k0 + ks;
        const float* wp = W + (size_t)(j0 + lrow) * K + k0 + ks;
#pragma unroll
        for (int q = 0; q < 8; ++q) {
            const int k = k0 + ks + q;
            Xs[ks + q][lrow] = (k < K) ? xp[q] : 0.f;
            Ws[ks + q][lrow] = (k < K) ? wp[q] : 0.f;
        }
        __syncthreads();
#pragma unroll 8
        for (int kk = 0; kk < 32; ++kk) {
            const float4 xv = *(const float4*)&Xs[kk][ti * 4];
            const float4 wv = *(const float4*)&Ws[kk][tj * 4];
            acc[0][0] = fmaf(xv.x, wv.x, acc[0][0]);
            acc[0][1] = fmaf(xv.x, wv.y, acc[0][1]);
            acc[0][2] = fmaf(xv.x, wv.z, acc[0][2]);
            acc[0][3] = fmaf(xv.x, wv.w, acc[0][3]);
            acc[1][0] = fmaf(xv.y, wv.x, acc[1][0]);
            acc[1][1] = fmaf(xv.y, wv.y, acc[1][1]);
            acc[1][2] = fmaf(xv.y, wv.z, acc[1][2]);
            acc[1][3] = fmaf(xv.y, wv.w, acc[1][3]);
            acc[2][0] = fmaf(xv.z, wv.x, acc[2][0]);
            acc[2][1] = fmaf(xv.z, wv.y, acc[2][1]);
            acc[2][2] = fmaf(xv.z, wv.z, acc[2][2]);
            acc[2][3] = fmaf(xv.z, wv.w, acc[2][3]);
            acc[3][0] = fmaf(xv.w, wv.x, acc[3][0]);
            acc[3][1] = fmaf(xv.w, wv.y, acc[3][1]);
            acc[3][2] = fmaf(xv.w, wv.z, acc[3][2]);
            acc[3][3] = fmaf(xv.w, wv.w, acc[3][3]);
        }
        __syncthreads();
    }
#pragma unroll
    for (int i = 0; i < 4; ++i) {
        const int m = m0 + ti * 4 + i;
#pragma unroll
        for (int j = 0; j < 4; ++j) {
            const int jj = j0 + tj * 4 + j;
            if (NZ == 1) Y[(size_t)m * J + jj] = acc[i][j] + bias[jj];
            else         Y[(size_t)m * J + jj] = acc[i][j];
        }
    }
}

// ---------------------------------------------------------------------------
// K5b: sum NZ split-K partials + bias -> xl2 / xr2. float4 per thread.
// ---------------------------------------------------------------------------
template <int NZ>
__global__ __launch_bounds__(256) void reduce_kernel(
    const float* __restrict__ P, const float* __restrict__ bl, const float* __restrict__ br,
    float* __restrict__ Yl, float* __restrict__ Yr)
{
    const int idx = blockIdx.x * 256 + threadIdx.x;          // float4 index
    const int per_side = NNODE * 64 / 4;                     // 79872
    if (idx >= 2 * per_side) return;
    const int side = idx >= per_side;
    const int r = idx - side * per_side;
    const int j4 = (r & 15);

    const float4* __restrict__ P4 = (const float4*)P;
    float4 acc = P4[(size_t)side * per_side + r];
#pragma unroll
    for (int z = 1; z < NZ; ++z) {
        const float4 v = P4[((size_t)z * 2 + side) * per_side + r];
        acc.x += v.x; acc.y += v.y; acc.z += v.z; acc.w += v.w;
    }
    const float4 bv = *(const float4*)((side ? br : bl) + j4 * 4);
    acc.x += bv.x; acc.y += bv.y; acc.z += bv.z; acc.w += bv.w;
    ((float4*)(side ? Yr : Yl))[r] = acc;
}

// ---------------------------------------------------------------------------
// K6: single-pass no-max softmax GATv2 (at random-gather traffic floor:
// 135 MB compulsory @ 2.79 TB/s). Wave = (node, head); no LDS.
// ---------------------------------------------------------------------------
template <int FDIM>
static __device__ __forceinline__ void gat_nomax(
    const float* __restrict__ xl, const int* __restrict__ srcs,
    int base, int deg, int hoff, int lane, float4 xrv, float4 av,
    float4& accOut, float& lOut)
{
    const int e4 = lane >> 4;
    const int c4 = lane & 15;
    float l = 0.f;
    float4 acc = make_float4(0.f, 0.f, 0.f, 0.f);

    for (int c0 = 0; c0 < deg; c0 += 8) {
        const int eA = c0 + e4;
        const int eB = c0 + 4 + e4;
        const int sA = srcs[base + min(eA, deg - 1)];
        const int sB = srcs[base + min(eB, deg - 1)];
        const float4 xaA = *(const float4*)(xl + (size_t)sA * FDIM + hoff + c4 * 4);
        const float4 xaB = *(const float4*)(xl + (size_t)sB * FDIM + hoff + c4 * 4);

        float a0 = xaA.x + xrv.x; a0 = fmaxf(a0, 0.2f * a0);
        float a1 = xaA.y + xrv.y; a1 = fmaxf(a1, 0.2f * a1);
        float a2 = xaA.z + xrv.z; a2 = fmaxf(a2, 0.2f * a2);
        float a3 = xaA.w + xrv.w; a3 = fmaxf(a3, 0.2f * a3);
        float pA = av.x * a0 + av.y * a1 + av.z * a2 + av.w * a3;
        float b0 = xaB.x + xrv.x; b0 = fmaxf(b0, 0.2f * b0);
        float b1 = xaB.y + xrv.y; b1 = fmaxf(b1, 0.2f * b1);
        float b2 = xaB.z + xrv.z; b2 = fmaxf(b2, 0.2f * b2);
        float b3 = xaB.w + xrv.w; b3 = fmaxf(b3, 0.2f * b3);
        float pB = av.x * b0 + av.y * b1 + av.z * b2 + av.w * b3;

        pA += __shfl_xor(pA, 1, 64);
        pA += __shfl_xor(pA, 2, 64);
        pA += __shfl_xor(pA, 4, 64);
        pA += __shfl_xor(pA, 8, 64);
        pB += __shfl_xor(pB, 1, 64);
        pB += __shfl_xor(pB, 2, 64);
        pB += __shfl_xor(pB, 4, 64);
        pB += __shfl_xor(pB, 8, 64);

        const float wA = (eA < deg) ? __expf(pA) : 0.f;
        const float wB = (eB < deg) ? __expf(pB) : 0.f;
        l += wA + wB;
        acc.x = fmaf(wA, xaA.x, fmaf(wB, xaB.x, acc.x));
        acc.y = fmaf(wA, xaA.y, fmaf(wB, xaB.y, acc.y));
        acc.z = fmaf(wA, xaA.z, fmaf(wB, xaB.z, acc.z));
        acc.w = fmaf(wA, xaA.w, fmaf(wB, xaB.w, acc.w));
    }

    l += __shfl_xor(l, 16, 64);
    l += __shfl_xor(l, 32, 64);
    acc.x += __shfl_xor(acc.x, 16, 64);
    acc.y += __shfl_xor(acc.y, 16, 64);
    acc.z += __shfl_xor(acc.z, 16, 64);
    acc.w += __shfl_xor(acc.w, 16, 64);
    acc.x += __shfl_xor(acc.x, 32, 64);
    acc.y += __shfl_xor(acc.y, 32, 64);
    acc.z += __shfl_xor(acc.z, 32, 64);
    acc.w += __shfl_xor(acc.w, 32, 64);
    accOut = acc;
    lOut = l;
}

__global__ __launch_bounds__(512) void gat1_fused_kernel(
    const float* __restrict__ xl, const float* __restrict__ xr,
    const float* __restrict__ att, const float* __restrict__ bias,
    const int* __restrict__ offsets, const int* __restrict__ srcs,
    float* __restrict__ h1)
{
    const int n = blockIdx.x;
    const int h = threadIdx.x >> 6;
    const int lane = threadIdx.x & 63;
    const int base = offsets[n];
    const int deg = offsets[n + 1] - base;
    const int c4 = lane & 15;

    const float4 xrv = *(const float4*)(xr + (size_t)n * F1 + h * 64 + c4 * 4);
    const float4 av  = *(const float4*)(att + h * 64 + c4 * 4);

    float4 acc; float l;
    gat_nomax<F1>(xl, srcs, base, deg, h * 64, lane, xrv, av, acc, l);

    if ((lane >> 4) == 0) {
        const float inv = 1.f / l;
        const float4 bv = *(const float4*)(bias + h * 64 + c4 * 4);
        float4 o;
        o.x = acc.x * inv + bv.x; o.x = (o.x > 0.f) ? o.x : expm1f(o.x);
        o.y = acc.y * inv + bv.y; o.y = (o.y > 0.f) ? o.y : expm1f(o.y);
        o.z = acc.z * inv + bv.z; o.z = (o.z > 0.f) ? o.z : expm1f(o.z);
        o.w = acc.w * inv + bv.w; o.w = (o.w > 0.f) ? o.w : expm1f(o.w);
        *(float4*)(h1 + (size_t)n * F1 + h * 64 + c4 * 4) = o;
    }
}

__global__ __launch_bounds__(256) void gat2_fused_kernel(
    const float* __restrict__ xl, const float* __restrict__ xr,
    const float* __restrict__ att, const float* __restrict__ bias,
    const int* __restrict__ offsets, const int* __restrict__ srcs,
    float* __restrict__ out)
{
    const int wv = threadIdx.x >> 6;
    const int lane = threadIdx.x & 63;
    const int n = blockIdx.x * 4 + wv;
    const int base = offsets[n];
    const int deg = offsets[n + 1] - base;
    const int c4 = lane & 15;

    const float4 xrv = *(const float4*)(xr + (size_t)n * F2 + c4 * 4);
    const float4 av  = *(const float4*)(att + c4 * 4);

    float4 acc; float l;
    gat_nomax<F2>(xl, srcs, base, deg, 0, lane, xrv, av, acc, l);

    if ((lane >> 4) == 0) {
        const float inv = 1.f / l;
        const float4 bv = *(const float4*)(bias + c4 * 4);
        float4 o;
        o.x = acc.x * inv + bv.x;
        o.y = acc.y * inv + bv.y;
        o.z = acc.z * inv + bv.z;
        o.w = acc.w * inv + bv.w;
        *(float4*)(out + (size_t)n * F2 + c4 * 4) = o;
    }
}

// ---------------------------------------------------------------------------
extern "C" void kernel_launch(void* const* d_in, const int* in_sizes, int n_in,
                              void* d_out, int out_size, void* d_ws, size_t ws_size,
                              hipStream_t stream)
{
    const int*   ei    = (const int*)d_in[0];
    const float* ve    = (const float*)d_in[1];
    const float* ac    = (const float*)d_in[2];
    const float* man   = (const float*)d_in[3];
    const float* maskv = (const float*)d_in[4];
    const float* c1w   = (const float*)d_in[6];
    const float* c1b   = (const float*)d_in[7];
    const float* bn1g  = (const float*)d_in[8];
    const float* bn1b  = (const float*)d_in[9];
    const float* c2w   = (const float*)d_in[10];
    const float* c2b   = (const float*)d_in[11];
    const float* bn2g  = (const float*)d_in[12];
    const float* bn2b  = (const float*)d_in[13];
    const float* wih   = (const float*)d_in[14];
    const float* whh   = (const float*)d_in[15];
    const float* bih   = (const float*)d_in[16];
    const float* bhh   = (const float*)d_in[17];
    const float* g1wl  = (const float*)d_in[18];
    const float* g1bl  = (const float*)d_in[19];
    const float* g1wr  = (const float*)d_in[20];
    const float* g1br  = (const float*)d_in[21];
    const float* g1att = (const float*)d_in[22];
    const float* g1bias= (const float*)d_in[23];
    const float* g2wl  = (const float*)d_in[24];
    const float* g2bl  = (const float*)d_in[25];
    const float* g2wr  = (const float*)d_in[26];
    const float* g2br  = (const float*)d_in[27];
    const float* g2att = (const float*)d_in[28];
    const float* g2bias= (const float*)d_in[29];
    float* outp = (float*)d_out;

    // workspace layout (floats)
    float* ws     = (float*)d_ws;
    float* gi     = ws;                         // 3 * 194688 = 584064
    float* xn     = gi     + 584064;            // 389376
    float* xl1    = xn     + 389376;            // 2555904
    float* xr1    = xl1    + 2555904;           // 2555904
    float* h1     = xr1    + 2555904;           // 2555904
    float* xl2    = h1     + 2555904;           // 319488
    float* xr2    = xl2    + 319488;            // 319488
    int* counts  = (int*)(xr2 + 319488);        // 4992
    int* offsets = counts + NNODE;              // 4993
    int* cursor  = offsets + NNODE + 1;         // 4992
    int* srcs    = cursor + NNODE;              // 205056

    // split-K partials overlay xl1+xr1 (both dead after gat1_fused):
    // 8 z-chunks x 2 sides x 319488 = 5111808 floats = xl1+xr1 exactly.
    float* part = xl1;

    hipMemsetAsync(counts, 0, NNODE * sizeof(int), stream);

    conv_kernel<<<dim3(NBATCH, (HN + CROWS - 1) / CROWS), 256, 0, stream>>>(
        ve, ac, man, c1w, c1b, bn1g, bn1b, c2w, c2b, bn2g, bn2b, wih, bih,
        maskv, gi, xn);
    gru_kernel<<<(NNODE + 63) / 64, 64, 0, stream>>>(gi, whh, bhh, maskv, xn);

    edge_hist<<<(E_TOT + 255) / 256, 256, 0, stream>>>(ei, counts);
    scan_kernel<<<1, 256, 0, stream>>>(counts, offsets, cursor);
    edge_scatter<<<(E_TOT + 255) / 256, 256, 0, stream>>>(ei, cursor, srcs);

    gemm_kernel<78, 1><<<dim3(NNODE / 64, 2 * (F1 / 64)), 256, 0, stream>>>(
        xn, g1wl, g1bl, g1wr, g1br, xl1, xr1, F1);

    gat1_fused_kernel<<<NNODE, 512, 0, stream>>>(xl1, xr1, g1att, g1bias, offsets, srcs, h1);

    gemm_kernel<512, 8><<<dim3(NNODE / 64, 2 * (F2 / 64), 8), 256, 0, stream>>>(
        h1, g2wl, g2bl, g2wr, g2br, part, nullptr, F2);
    reduce_kernel<8><<<(2 * NNODE * 64 / 4 + 255) / 256, 256, 0, stream>>>(
        part, g2bl, g2br, xl2, xr2);

    gat2_fused_kernel<<<NNODE / 4, 256, 0, stream>>>(xl2, xr2, g2att, g2bias, offsets, srcs, outp);
}

// Round 17
// 280.255 us; speedup vs baseline: 1.1690x; 1.0927x over previous
//
#include <hip/hip_runtime.h>
#include <hip/hip_bf16.h>
#include <math.h>

#define HN 39
#define WN 39
#define NBATCH 128
#define NPIX (HN * WN)          // 1521
#define NNODE (NBATCH * WN)     // 4992
#define E_RAW 200064
#define E_TOT (E_RAW + NNODE)   // 205056
#define F1 512
#define F2 64
#define CROWS 6                 // conv output rows per block
#define GIPL (NBATCH * NPIX)    // gi plane stride = 194688
#define HIST_BLKS 802           // ceil(E_TOT/256)
#define GRU_BLKS 20             // ceil(NNODE/256)

static __device__ __forceinline__ float nan0(float x) { return (x == x) ? x : 0.f; }
static __device__ __forceinline__ float sigmoid_f(float x) { return 1.f / (1.f + __expf(-x)); }
static __device__ __forceinline__ float tanh_f(float x) {
    float e = __expf(2.f * x);
    return 1.f - 2.f / (e + 1.f);
}

#define BN_RSQ 0.99999500003749969f   // 1/sqrt(1+1e-5)

// ---------------------------------------------------------------------------
// K1: fused nan-clean + conv1+BN+ReLU + conv2+BN + GRU input proj.
// R16: blockIdx.y==0 blocks also zero counts (eliminates the memset node).
// ---------------------------------------------------------------------------
__global__ __launch_bounds__(256) void conv_kernel(
    const float* __restrict__ ve, const float* __restrict__ ac, const float* __restrict__ man,
    const float* __restrict__ c1w, const float* __restrict__ c1b,
    const float* __restrict__ bn1g, const float* __restrict__ bn1b,
    const float* __restrict__ c2w, const float* __restrict__ c2b,
    const float* __restrict__ bn2g, const float* __restrict__ bn2b,
    const float* __restrict__ wih, const float* __restrict__ bih,
    const float* __restrict__ maskv,
    float* __restrict__ gi_out,      // 3 planes of (B,1521)
    float* __restrict__ xn,          // (NNODE, 78)
    int* __restrict__ counts)
{
    __shared__ float y1[8][(CROWS + 2) * WN + 8];
    const int b = blockIdx.x;
    const int r0 = blockIdx.y * CROWS;
    const int tid = threadIdx.x;

    if (blockIdx.y == 0 && tid < WN) counts[b * WN + tid] = 0;   // memset fold-in

    for (int p = tid; p < (CROWS + 2) * WN; p += 256) {
        const int row = p / WN;
        const int hh = r0 - 1 + row;
        if (hh < 0 || hh >= HN) continue;
        const int w = p - row * WN;
        const int gidx = b * NPIX + hh * WN + w;
        const float m = nan0(man[gidx]);
        const float a = nan0(ac[gidx]);
        const float v = nan0(ve[gidx]);
        if (hh >= r0 && hh < r0 + CROWS)
            xn[(size_t)(b * WN + w) * 78 + hh] = m * maskv[b * WN + w];
#pragma unroll
        for (int c = 0; c < 8; ++c) {
            float val = c1w[c * 3 + 0] * m + c1w[c * 3 + 1] * a + c1w[c * 3 + 2] * v + c1b[c];
            val = val * (bn1g[c] * BN_RSQ) + bn1b[c];
            y1[c][p] = fmaxf(val, 0.f);
        }
    }
    __syncthreads();

    for (int p = tid; p < CROWS * WN; p += 256) {
        const int h = r0 + p / WN;
        if (h >= HN) continue;
        const int w = p - (p / WN) * WN;
        float acc[16];
#pragma unroll
        for (int o = 0; o < 16; ++o) acc[o] = 0.f;
        for (int c = 0; c < 8; ++c) {
#pragma unroll
            for (int dy = 0; dy < 3; ++dy) {
                const int hh = h + dy - 1;
                if (hh < 0 || hh >= HN) continue;
                const int lrow = hh - r0 + 1;
#pragma unroll
                for (int dx = 0; dx < 3; ++dx) {
                    const int ww = w + dx - 1;
                    if (ww < 0 || ww >= WN) continue;
                    const float yv = y1[c][lrow * WN + ww];
#pragma unroll
                    for (int o = 0; o < 16; ++o)
                        acc[o] = fmaf(c2w[((o * 8 + c) * 3 + dy) * 3 + dx], yv, acc[o]);
                }
            }
        }
        float gi0 = bih[0], gi1 = bih[1], gi2 = bih[2];
#pragma unroll
        for (int o = 0; o < 16; ++o) {
            const float x2 = (acc[o] + c2b[o]) * (bn2g[o] * BN_RSQ) + bn2b[o];
            gi0 = fmaf(wih[0 * 16 + o], x2, gi0);
            gi1 = fmaf(wih[1 * 16 + o], x2, gi1);
            gi2 = fmaf(wih[2 * 16 + o], x2, gi2);
        }
        const int idx = b * NPIX + h * WN + w;
        gi_out[idx] = gi0;
        gi_out[GIPL + idx] = gi1;
        gi_out[2 * GIPL + idx] = gi2;
    }
}

// ---------------------------------------------------------------------------
// K2 (R16): fused GRU recurrence + edge histogram (independent work items;
// branch on blockIdx — saves one graph node).
// ---------------------------------------------------------------------------
__global__ __launch_bounds__(256) void gru_hist_kernel(
    const float* __restrict__ gi, const float* __restrict__ whh, const float* __restrict__ bhh,
    const float* __restrict__ maskv, float* __restrict__ xn,
    const int* __restrict__ ei, int* __restrict__ counts)
{
    const int blk = blockIdx.x;
    if (blk < GRU_BLKS) {
        const int idx = blk * 256 + threadIdx.x;
        if (idx >= NNODE) return;
        const int b = idx / WN, w = idx - (idx / WN) * WN;
        const float mk = maskv[idx];
        float* __restrict__ xrow = xn + (size_t)idx * 78 + HN;

        const float* __restrict__ g0 = gi + b * NPIX + w;
        const float* __restrict__ g1 = g0 + GIPL;
        const float* __restrict__ g2 = g0 + 2 * GIPL;

        const float wh0 = whh[0], wh1 = whh[1], wh2 = whh[2];
        const float bh0 = bhh[0], bh1 = bhh[1], bh2 = bhh[2];
        float h = 0.f;
#pragma unroll 1
        for (int t = 0; t < HN; t += 3) {       // 39 = 13 * 3
            const float ga0 = g0[t * WN],       ga1 = g1[t * WN],       ga2 = g2[t * WN];
            const float gb0 = g0[(t + 1) * WN], gb1 = g1[(t + 1) * WN], gb2 = g2[(t + 1) * WN];
            const float gc0 = g0[(t + 2) * WN], gc1 = g1[(t + 2) * WN], gc2 = g2[(t + 2) * WN];

            float r = sigmoid_f(ga0 + h * wh0 + bh0);
            float z = sigmoid_f(ga1 + h * wh1 + bh1);
            float n = tanh_f(ga2 + r * (h * wh2 + bh2));
            h = (1.f - z) * n + z * h;
            xrow[t] = h * mk;

            r = sigmoid_f(gb0 + h * wh0 + bh0);
            z = sigmoid_f(gb1 + h * wh1 + bh1);
            n = tanh_f(gb2 + r * (h * wh2 + bh2));
            h = (1.f - z) * n + z * h;
            xrow[t + 1] = h * mk;

            r = sigmoid_f(gc0 + h * wh0 + bh0);
            z = sigmoid_f(gc1 + h * wh1 + bh1);
            n = tanh_f(gc2 + r * (h * wh2 + bh2));
            h = (1.f - z) * n + z * h;
            xrow[t + 2] = h * mk;
        }
    } else {
        const int e = (blk - GRU_BLKS) * 256 + threadIdx.x;
        if (e >= E_TOT) return;
        const int d = (e < E_RAW) ? ei[E_RAW + e] : (e - E_RAW);
        atomicAdd(&counts[d], 1);
    }
}

// ---------------------------------------------------------------------------
// K4: prefix scan (1 block)
// ---------------------------------------------------------------------------
__global__ __launch_bounds__(256) void scan_kernel(const int* __restrict__ counts,
                                                   int* __restrict__ offsets, int* __restrict__ cursor)
{
    __shared__ int sums[256];
    const int tid = threadIdx.x;
    const int start = tid * 20;
    const int end = min(start + 20, NNODE);
    int s = 0;
    for (int i = start; i < end; ++i) s += counts[i];
    sums[tid] = s;
    __syncthreads();
    for (int off = 1; off < 256; off <<= 1) {
        int v = (tid >= off) ? sums[tid - off] : 0;
        __syncthreads();
        sums[tid] += v;
        __syncthreads();
    }
    int run = (tid == 0) ? 0 : sums[tid - 1];
    for (int i = start; i < end; ++i) {
        offsets[i] = run;
        cursor[i] = run;
        run += counts[i];
    }
    if (tid == 255) offsets[NNODE] = run;
}

// ---------------------------------------------------------------------------
// K5 (R16): fused edge_scatter + gemm78 (independent; branch on blockIdx —
// saves one graph node). Blocks 0..801 scatter; 802..2049 do the xn GEMM.
// ---------------------------------------------------------------------------
__global__ __launch_bounds__(256) void scatter_gemm78_kernel(
    const int* __restrict__ ei, int* __restrict__ cursor, int* __restrict__ srcs,
    const float* __restrict__ X,
    const float* __restrict__ Wl, const float* __restrict__ bl,
    const float* __restrict__ Wr, const float* __restrict__ br,
    float* __restrict__ Yl, float* __restrict__ Yr)
{
    if (blockIdx.x < HIST_BLKS) {
        const int e = blockIdx.x * 256 + threadIdx.x;
        if (e >= E_TOT) return;
        int s, d;
        if (e < E_RAW) { s = ei[e]; d = ei[E_RAW + e]; }
        else           { s = d = e - E_RAW; }
        const int pos = atomicAdd(&cursor[d], 1);
        srcs[pos] = s;
        return;
    }

    // gemm78: Y = X(4992,78) @ W(512,78)^T + b for both sides
    const int bx = blockIdx.x - HIST_BLKS;         // 0..1247
    const int m0 = (bx % 78) * 64;
    const int yt = bx / 78;                        // 0..15
    const int sel = (yt >= 8) ? 1 : 0;
    const int j0 = (yt - sel * 8) * 64;
    const float* __restrict__ W = sel ? Wr : Wl;
    const float* __restrict__ bias = sel ? br : bl;
    float* __restrict__ Y = sel ? Yr : Yl;
    const int K = 78, J = F1;

    __shared__ __align__(16) float Xs[32][68];
    __shared__ __align__(16) float Ws[32][68];

    const int tid = threadIdx.x;
    const int ti = tid / 16, tj = tid & 15;
    const int lrow = tid >> 2;
    const int ks = (tid & 3) * 8;

    float acc[4][4];
#pragma unroll
    for (int i = 0; i < 4; ++i)
#pragma unroll
        for (int j = 0; j < 4; ++j) acc[i][j] = 0.f;

    for (int k0 = 0; k0 < K; k0 += 32) {
        const float* xp = X + (size_t)(m0 + lrow) * K + k0 + ks;
        const float* wp = W + (size_t)(j0 + lrow) * K + k0 + ks;
#pragma unroll
        for (int q = 0; q < 8; ++q) {
            const int k = k0 + ks + q;
            Xs[ks + q][lrow] = (k < K) ? xp[q] : 0.f;
            Ws[ks + q][lrow] = (k < K) ? wp[q] : 0.f;
        }
        __syncthreads();
#pragma unroll 8
        for (int kk = 0; kk < 32; ++kk) {
            const float4 xv = *(const float4*)&Xs[kk][ti * 4];
            const float4 wv = *(const float4*)&Ws[kk][tj * 4];
            acc[0][0] = fmaf(xv.x, wv.x, acc[0][0]);
            acc[0][1] = fmaf(xv.x, wv.y, acc[0][1]);
            acc[0][2] = fmaf(xv.x, wv.z, acc[0][2]);
            acc[0][3] = fmaf(xv.x, wv.w, acc[0][3]);
            acc[1][0] = fmaf(xv.y, wv.x, acc[1][0]);
            acc[1][1] = fmaf(xv.y, wv.y, acc[1][1]);
            acc[1][2] = fmaf(xv.y, wv.z, acc[1][2]);
            acc[1][3] = fmaf(xv.y, wv.w, acc[1][3]);
            acc[2][0] = fmaf(xv.z, wv.x, acc[2][0]);
            acc[2][1] = fmaf(xv.z, wv.y, acc[2][1]);
            acc[2][2] = fmaf(xv.z, wv.z, acc[2][2]);
            acc[2][3] = fmaf(xv.z, wv.w, acc[2][3]);
            acc[3][0] = fmaf(xv.w, wv.x, acc[3][0]);
            acc[3][1] = fmaf(xv.w, wv.y, acc[3][1]);
            acc[3][2] = fmaf(xv.w, wv.z, acc[3][2]);
            acc[3][3] = fmaf(xv.w, wv.w, acc[3][3]);
        }
        __syncthreads();
    }
#pragma unroll
    for (int i = 0; i < 4; ++i) {
        const int m = m0 + ti * 4 + i;
#pragma unroll
        for (int j = 0; j < 4; ++j) {
            const int jj = j0 + tj * 4 + j;
            Y[(size_t)m * J + jj] = acc[i][j] + bias[jj];
        }
    }
}

// ---------------------------------------------------------------------------
// K6: tiled f32 GEMM, split-K NZ=8 disjoint partials (R15: 64us->sub-top5).
// ---------------------------------------------------------------------------
template <int K, int NZ>
__global__ __launch_bounds__(256, 4) void gemm_kernel(
    const float* __restrict__ X,
    const float* __restrict__ Wl, const float* __restrict__ bl,
    const float* __restrict__ Wr, const float* __restrict__ br,
    float* __restrict__ Yl, float* __restrict__ Yr, int J)
{
    const int nyb = J >> 6;
    const int sel = (blockIdx.y >= nyb) ? 1 : 0;
    const int j0 = (blockIdx.y - sel * nyb) * 64;
    const float* __restrict__ W = sel ? Wr : Wl;
    const float* __restrict__ bias = sel ? br : bl;
    float* __restrict__ Y;
    if (NZ == 1) Y = sel ? Yr : Yl;
    else         Y = Yl + ((size_t)blockIdx.z * 2 + sel) * ((size_t)NNODE * J);

    __shared__ __align__(16) float Xs[32][68];
    __shared__ __align__(16) float Ws[32][68];

    const int kchunk = K / NZ;
    const int kbeg = blockIdx.z * kchunk;
    const int kend = (blockIdx.z == NZ - 1) ? K : kbeg + kchunk;

    const int m0 = blockIdx.x * 64;
    const int tid = threadIdx.x;
    const int ti = tid / 16, tj = tid & 15;
    const int lrow = tid >> 2;
    const int ks = (tid & 3) * 8;

    float acc[4][4];
#pragma unroll
    for (int i = 0; i < 4; ++i)
#pragma unroll
        for (int j = 0; j < 4; ++j) acc[i][j] = 0.f;

    for (int k0 = kbeg; k0 < kend; k0 += 32) {
        const float* xp = X + (size_t)(m0 + lrow) * K + k0 + ks;
        const float* wp = W + (size_t)(j0 + lrow) * K + k0 + ks;
#pragma unroll
        for (int q = 0; q < 8; ++q) {
            const int k = k0 + ks + q;
            Xs[ks + q][lrow] = (k < K) ? xp[q] : 0.f;
            Ws[ks + q][lrow] = (k < K) ? wp[q] : 0.f;
        }
        __syncthreads();
#pragma unroll 8
        for (int kk = 0; kk < 32; ++kk) {
            const float4 xv = *(const float4*)&Xs[kk][ti * 4];
            const float4 wv = *(const float4*)&Ws[kk][tj * 4];
            acc[0][0] = fmaf(xv.x, wv.x, acc[0][0]);
            acc[0][1] = fmaf(xv.x, wv.y, acc[0][1]);
            acc[0][2] = fmaf(xv.x, wv.z, acc[0][2]);
            acc[0][3] = fmaf(xv.x, wv.w, acc[0][3]);
            acc[1][0] = fmaf(xv.y, wv.x, acc[1][0]);
            acc[1][1] = fmaf(xv.y, wv.y, acc[1][1]);
            acc[1][2] = fmaf(xv.y, wv.z, acc[1][2]);
            acc[1][3] = fmaf(xv.y, wv.w, acc[1][3]);
            acc[2][0] = fmaf(xv.z, wv.x, acc[2][0]);
            acc[2][1] = fmaf(xv.z, wv.y, acc[2][1]);
            acc[2][2] = fmaf(xv.z, wv.z, acc[2][2]);
            acc[2][3] = fmaf(xv.z, wv.w, acc[2][3]);
            acc[3][0] = fmaf(xv.w, wv.x, acc[3][0]);
            acc[3][1] = fmaf(xv.w, wv.y, acc[3][1]);
            acc[3][2] = fmaf(xv.w, wv.z, acc[3][2]);
            acc[3][3] = fmaf(xv.w, wv.w, acc[3][3]);
        }
        __syncthreads();
    }
#pragma unroll
    for (int i = 0; i < 4; ++i) {
        const int m = m0 + ti * 4 + i;
#pragma unroll
        for (int j = 0; j < 4; ++j) {
            const int jj = j0 + tj * 4 + j;
            if (NZ == 1) Y[(size_t)m * J + jj] = acc[i][j] + bias[jj];
            else         Y[(size_t)m * J + jj] = acc[i][j];
        }
    }
}

// ---------------------------------------------------------------------------
// K6b: sum NZ split-K partials + bias -> xl2 / xr2.
// ---------------------------------------------------------------------------
template <int NZ>
__global__ __launch_bounds__(256) void reduce_kernel(
    const float* __restrict__ P, const float* __restrict__ bl, const float* __restrict__ br,
    float* __restrict__ Yl, float* __restrict__ Yr)
{
    const int idx = blockIdx.x * 256 + threadIdx.x;
    const int per_side = NNODE * 64 / 4;                     // 79872
    if (idx >= 2 * per_side) return;
    const int side = idx >= per_side;
    const int r = idx - side * per_side;
    const int j4 = (r & 15);

    const float4* __restrict__ P4 = (const float4*)P;
    float4 acc = P4[(size_t)side * per_side + r];
#pragma unroll
    for (int z = 1; z < NZ; ++z) {
        const float4 v = P4[((size_t)z * 2 + side) * per_side + r];
        acc.x += v.x; acc.y += v.y; acc.z += v.z; acc.w += v.w;
    }
    const float4 bv = *(const float4*)((side ? br : bl) + j4 * 4);
    acc.x += bv.x; acc.y += bv.y; acc.z += bv.z; acc.w += bv.w;
    ((float4*)(side ? Yr : Yl))[r] = acc;
}

// ---------------------------------------------------------------------------
// K7: single-pass no-max softmax GATv2 (at random-gather traffic floor).
// ---------------------------------------------------------------------------
template <int FDIM>
static __device__ __forceinline__ void gat_nomax(
    const float* __restrict__ xl, const int* __restrict__ srcs,
    int base, int deg, int hoff, int lane, float4 xrv, float4 av,
    float4& accOut, float& lOut)
{
    const int e4 = lane >> 4;
    const int c4 = lane & 15;
    float l = 0.f;
    float4 acc = make_float4(0.f, 0.f, 0.f, 0.f);

    for (int c0 = 0; c0 < deg; c0 += 8) {
        const int eA = c0 + e4;
        const int eB = c0 + 4 + e4;
        const int sA = srcs[base + min(eA, deg - 1)];
        const int sB = srcs[base + min(eB, deg - 1)];
        const float4 xaA = *(const float4*)(xl + (size_t)sA * FDIM + hoff + c4 * 4);
        const float4 xaB = *(const float4*)(xl + (size_t)sB * FDIM + hoff + c4 * 4);

        float a0 = xaA.x + xrv.x; a0 = fmaxf(a0, 0.2f * a0);
        float a1 = xaA.y + xrv.y; a1 = fmaxf(a1, 0.2f * a1);
        float a2 = xaA.z + xrv.z; a2 = fmaxf(a2, 0.2f * a2);
        float a3 = xaA.w + xrv.w; a3 = fmaxf(a3, 0.2f * a3);
        float pA = av.x * a0 + av.y * a1 + av.z * a2 + av.w * a3;
        float b0 = xaB.x + xrv.x; b0 = fmaxf(b0, 0.2f * b0);
        float b1 = xaB.y + xrv.y; b1 = fmaxf(b1, 0.2f * b1);
        float b2 = xaB.z + xrv.z; b2 = fmaxf(b2, 0.2f * b2);
        float b3 = xaB.w + xrv.w; b3 = fmaxf(b3, 0.2f * b3);
        float pB = av.x * b0 + av.y * b1 + av.z * b2 + av.w * b3;

        pA += __shfl_xor(pA, 1, 64);
        pA += __shfl_xor(pA, 2, 64);
        pA += __shfl_xor(pA, 4, 64);
        pA += __shfl_xor(pA, 8, 64);
        pB += __shfl_xor(pB, 1, 64);
        pB += __shfl_xor(pB, 2, 64);
        pB += __shfl_xor(pB, 4, 64);
        pB += __shfl_xor(pB, 8, 64);

        const float wA = (eA < deg) ? __expf(pA) : 0.f;
        const float wB = (eB < deg) ? __expf(pB) : 0.f;
        l += wA + wB;
        acc.x = fmaf(wA, xaA.x, fmaf(wB, xaB.x, acc.x));
        acc.y = fmaf(wA, xaA.y, fmaf(wB, xaB.y, acc.y));
        acc.z = fmaf(wA, xaA.z, fmaf(wB, xaB.z, acc.z));
        acc.w = fmaf(wA, xaA.w, fmaf(wB, xaB.w, acc.w));
    }

    l += __shfl_xor(l, 16, 64);
    l += __shfl_xor(l, 32, 64);
    acc.x += __shfl_xor(acc.x, 16, 64);
    acc.y += __shfl_xor(acc.y, 16, 64);
    acc.z += __shfl_xor(acc.z, 16, 64);
    acc.w += __shfl_xor(acc.w, 16, 64);
    acc.x += __shfl_xor(acc.x, 32, 64);
    acc.y += __shfl_xor(acc.y, 32, 64);
    acc.z += __shfl_xor(acc.z, 32, 64);
    acc.w += __shfl_xor(acc.w, 32, 64);
    accOut = acc;
    lOut = l;
}

__global__ __launch_bounds__(512) void gat1_fused_kernel(
    const float* __restrict__ xl, const float* __restrict__ xr,
    const float* __restrict__ att, const float* __restrict__ bias,
    const int* __restrict__ offsets, const int* __restrict__ srcs,
    float* __restrict__ h1)
{
    const int n = blockIdx.x;
    const int h = threadIdx.x >> 6;
    const int lane = threadIdx.x & 63;
    const int base = offsets[n];
    const int deg = offsets[n + 1] - base;
    const int c4 = lane & 15;

    const float4 xrv = *(const float4*)(xr + (size_t)n * F1 + h * 64 + c4 * 4);
    const float4 av  = *(const float4*)(att + h * 64 + c4 * 4);

    float4 acc; float l;
    gat_nomax<F1>(xl, srcs, base, deg, h * 64, lane, xrv, av, acc, l);

    if ((lane >> 4) == 0) {
        const float inv = 1.f / l;
        const float4 bv = *(const float4*)(bias + h * 64 + c4 * 4);
        float4 o;
        o.x = acc.x * inv + bv.x; o.x = (o.x > 0.f) ? o.x : expm1f(o.x);
        o.y = acc.y * inv + bv.y; o.y = (o.y > 0.f) ? o.y : expm1f(o.y);
        o.z = acc.z * inv + bv.z; o.z = (o.z > 0.f) ? o.z : expm1f(o.z);
        o.w = acc.w * inv + bv.w; o.w = (o.w > 0.f) ? o.w : expm1f(o.w);
        *(float4*)(h1 + (size_t)n * F1 + h * 64 + c4 * 4) = o;
    }
}

__global__ __launch_bounds__(256) void gat2_fused_kernel(
    const float* __restrict__ xl, const float* __restrict__ xr,
    const float* __restrict__ att, const float* __restrict__ bias,
    const int* __restrict__ offsets, const int* __restrict__ srcs,
    float* __restrict__ out)
{
    const int wv = threadIdx.x >> 6;
    const int lane = threadIdx.x & 63;
    const int n = blockIdx.x * 4 + wv;
    const int base = offsets[n];
    const int deg = offsets[n + 1] - base;
    const int c4 = lane & 15;

    const float4 xrv = *(const float4*)(xr + (size_t)n * F2 + c4 * 4);
    const float4 av  = *(const float4*)(att + c4 * 4);

    float4 acc; float l;
    gat_nomax<F2>(xl, srcs, base, deg, 0, lane, xrv, av, acc, l);

    if ((lane >> 4) == 0) {
        const float inv = 1.f / l;
        const float4 bv = *(const float4*)(bias + c4 * 4);
        float4 o;
        o.x = acc.x * inv + bv.x;
        o.y = acc.y * inv + bv.y;
        o.z = acc.z * inv + bv.z;
        o.w = acc.w * inv + bv.w;
        *(float4*)(out + (size_t)n * F2 + c4 * 4) = o;
    }
}

// ---------------------------------------------------------------------------
extern "C" void kernel_launch(void* const* d_in, const int* in_sizes, int n_in,
                              void* d_out, int out_size, void* d_ws, size_t ws_size,
                              hipStream_t stream)
{
    const int*   ei    = (const int*)d_in[0];
    const float* ve    = (const float*)d_in[1];
    const float* ac    = (const float*)d_in[2];
    const float* man   = (const float*)d_in[3];
    const float* maskv = (const float*)d_in[4];
    const float* c1w   = (const float*)d_in[6];
    const float* c1b   = (const float*)d_in[7];
    const float* bn1g  = (const float*)d_in[8];
    const float* bn1b  = (const float*)d_in[9];
    const float* c2w   = (const float*)d_in[10];
    const float* c2b   = (const float*)d_in[11];
    const float* bn2g  = (const float*)d_in[12];
    const float* bn2b  = (const float*)d_in[13];
    const float* wih   = (const float*)d_in[14];
    const float* whh   = (const float*)d_in[15];
    const float* bih   = (const float*)d_in[16];
    const float* bhh   = (const float*)d_in[17];
    const float* g1wl  = (const float*)d_in[18];
    const float* g1bl  = (const float*)d_in[19];
    const float* g1wr  = (const float*)d_in[20];
    const float* g1br  = (const float*)d_in[21];
    const float* g1att = (const float*)d_in[22];
    const float* g1bias= (const float*)d_in[23];
    const float* g2wl  = (const float*)d_in[24];
    const float* g2bl  = (const float*)d_in[25];
    const float* g2wr  = (const float*)d_in[26];
    const float* g2br  = (const float*)d_in[27];
    const float* g2att = (const float*)d_in[28];
    const float* g2bias= (const float*)d_in[29];
    float* outp = (float*)d_out;

    // workspace layout (floats)
    float* ws     = (float*)d_ws;
    float* gi     = ws;                         // 3 * 194688 = 584064
    float* xn     = gi     + 584064;            // 389376
    float* xl1    = xn     + 389376;            // 2555904
    float* xr1    = xl1    + 2555904;           // 2555904
    float* h1     = xr1    + 2555904;           // 2555904
    float* xl2    = h1     + 2555904;           // 319488
    float* xr2    = xl2    + 319488;            // 319488
    int* counts  = (int*)(xr2 + 319488);        // 4992
    int* offsets = counts + NNODE;              // 4993
    int* cursor  = offsets + NNODE + 1;         // 4992
    int* srcs    = cursor + NNODE;              // 205056

    // split-K partials overlay xl1+xr1 (dead after gat1_fused): 8*2*319488
    float* part = xl1;

    conv_kernel<<<dim3(NBATCH, (HN + CROWS - 1) / CROWS), 256, 0, stream>>>(
        ve, ac, man, c1w, c1b, bn1g, bn1b, c2w, c2b, bn2g, bn2b, wih, bih,
        maskv, gi, xn, counts);

    gru_hist_kernel<<<GRU_BLKS + HIST_BLKS, 256, 0, stream>>>(
        gi, whh, bhh, maskv, xn, ei, counts);

    scan_kernel<<<1, 256, 0, stream>>>(counts, offsets, cursor);

    scatter_gemm78_kernel<<<HIST_BLKS + 78 * 16, 256, 0, stream>>>(
        ei, cursor, srcs, xn, g1wl, g1bl, g1wr, g1br, xl1, xr1);

    gat1_fused_kernel<<<NNODE, 512, 0, stream>>>(xl1, xr1, g1att, g1bias, offsets, srcs, h1);

    gemm_kernel<512, 8><<<dim3(NNODE / 64, 2 * (F2 / 64), 8), 256, 0, stream>>>(
        h1, g2wl, g2bl, g2wr, g2br, part, nullptr, F2);
    reduce_kernel<8><<<(2 * NNODE * 64 / 4 + 255) / 256, 256, 0, stream>>>(
        part, g2bl, g2br, xl2, xr2);

    gat2_fused_kernel<<<NNODE / 4, 256, 0, stream>>>(xl2, xr2, g2att, g2bias, offsets, srcs, outp);
}